// Round 1
// 638.565 us; speedup vs baseline: 1.0031x; 1.0031x over previous
//
#include <hip/hip_runtime.h>
#include <hip/hip_bf16.h>

typedef __bf16 bf16;
typedef __attribute__((ext_vector_type(8))) __bf16 bf16x8;
typedef __attribute__((ext_vector_type(4))) float floatx4;

#define BATCH 8192
#define NREC  1024
#define DHID  2048

#define GLOBAL_AS __attribute__((address_space(1)))
#define LDS_AS    __attribute__((address_space(3)))

__device__ __forceinline__ bf16 to_bf16(float f) { return (bf16)f; }

// async global->LDS, 16 bytes per lane; LDS dest = wave-uniform base + lane*16
__device__ __forceinline__ void async16(const void* g, void* l) {
  __builtin_amdgcn_global_load_lds((const GLOBAL_AS unsigned int*)g,
                                   (LDS_AS unsigned int*)l, 16, 0, 0);
}

// Swizzled LDS fragment read: LDS tile is [128][32] bf16 (64 B rows, 4x 16B slots).
// Stored with slot s holding global slot s ^ ((row>>1)&3); read applies same XOR.
// Rows 0..7 then hit all 8 bank-quads -> 2-way aliasing (free) instead of 8-way.
__device__ __forceinline__ bf16x8 ldsFrag(const bf16* buf, int row, int q) {
  const int s = (q ^ ((row >> 1) & 3)) * 8;
  return *reinterpret_cast<const bf16x8*>(&buf[row * 32 + s]);
}

// ---------------- prep kernels ----------------

__global__ void lam_kernel(const float* __restrict__ nu, const float* __restrict__ theta,
                           float* __restrict__ lamRe, float* __restrict__ lamIm) {
  int h = blockIdx.x * blockDim.x + threadIdx.x;
  if (h < DHID) {
    float t = expf(-expf(nu[h]));
    lamRe[h] = t * cosf(theta[h]);
    lamIm[h] = t * sinf(theta[h]);
  }
}

// f32 -> bf16, 4 elements/thread
__global__ void convert_kernel(const float* __restrict__ src, bf16* __restrict__ dst) {
  int idx = blockIdx.x * blockDim.x + threadIdx.x;
  float4 v = reinterpret_cast<const float4*>(src)[idx];
  ushort4 pk;
  pk.x = __builtin_bit_cast(unsigned short, to_bf16(v.x));
  pk.y = __builtin_bit_cast(unsigned short, to_bf16(v.y));
  pk.z = __builtin_bit_cast(unsigned short, to_bf16(v.z));
  pk.w = __builtin_bit_cast(unsigned short, to_bf16(v.w));
  *reinterpret_cast<ushort4*>(dst + (size_t)idx * 4) = pk;
}

// dst[c*dstStride + r] = scale * src[r*C + c]; block (32,8); grid (C/32, R/32)
__global__ void transpose_kernel(const float* __restrict__ src, int C,
                                 bf16* __restrict__ dst, int dstStride, float scale) {
  __shared__ float tile[32][33];
  int c0 = blockIdx.x * 32, r0 = blockIdx.y * 32;
  #pragma unroll
  for (int i = 0; i < 32; i += 8) {
    tile[threadIdx.y + i][threadIdx.x] =
        src[(size_t)(r0 + threadIdx.y + i) * C + c0 + threadIdx.x];
  }
  __syncthreads();
  #pragma unroll
  for (int i = 0; i < 32; i += 8) {
    int c = c0 + threadIdx.y + i;
    dst[(size_t)c * dstStride + r0 + threadIdx.x] =
        to_bf16(scale * tile[threadIdx.x][threadIdx.y + i]);
  }
}

// ---------------- GEMM1: U_re/U_im = inputs @ B_{re,im}, fused recurrence epilogue ----
// A    [8192,1024] bf16 row-major
// BreT/BimT [2048,1024] bf16 (B^T layout: [h][k])
// out: xre/xim f32 [8192,2048]; Xcat bf16 [8192,4096] (cols 0..2047 = xre, 2048.. = xim)
//
// Double-buffered LDS: STAGE(t+1) issued BEFORE compute(t); single __syncthreads()
// per K-step (its vmcnt(0) drain overlaps the whole compute phase).

__global__ __launch_bounds__(256, 2) void gemm1_kernel(
    const bf16* __restrict__ A,
    const bf16* __restrict__ BreT,
    const bf16* __restrict__ BimT,
    const float* __restrict__ state_re,
    const float* __restrict__ state_im,
    const float* __restrict__ gamma,
    const float* __restrict__ lamRe,
    const float* __restrict__ lamIm,
    float* __restrict__ xre_out,
    float* __restrict__ xim_out,
    bf16* __restrict__ Xcat)
{
  __shared__ __align__(16) bf16 Alds[2][128 * 32];
  __shared__ __align__(16) bf16 BreLds[2][128 * 32];
  __shared__ __align__(16) bf16 BimLds[2][128 * 32];

  const int tid   = threadIdx.x;
  const int mBase = blockIdx.y * 128;
  const int hBase = blockIdx.x * 128;
  const int lane  = tid & 63;
  const int wave  = tid >> 6;
  const int wr    = (wave >> 1) * 64;
  const int wc    = (wave & 1) * 64;
  const int m16   = lane & 15;
  const int q     = lane >> 4;

  floatx4 zero = {0.f, 0.f, 0.f, 0.f};
  floatx4 accRe[4][4], accIm[4][4];
  #pragma unroll
  for (int i = 0; i < 4; ++i)
    #pragma unroll
    for (int j = 0; j < 4; ++j) { accRe[i][j] = zero; accIm[i][j] = zero; }

  const int row0 = tid >> 2;        // 0..63
  // wave-uniform LDS staging base: tile byte offset = tid*16 = wave*1024 + lane*16
  const int wbase = wave * 512;     // in bf16 elements

  // stage tile at K-offset kt into buffer `buf`; source slot pre-swizzled so the
  // linear global_load_lds write produces the swizzled LDS layout (rule #21).
  auto stage = [&](int buf, int kt) {
    #pragma unroll
    for (int p = 0; p < 2; ++p) {
      const int r  = row0 + p * 64;
      const int ss = ((tid & 3) ^ ((r >> 1) & 3)) * 8;   // swizzled 8-elem slot
      const size_t aoff = (size_t)(mBase + r) * 1024 + kt + ss;
      const size_t boff = (size_t)(hBase + r) * 1024 + kt + ss;
      async16(&A[aoff],    &Alds[buf][p * 2048 + wbase]);
      async16(&BreT[boff], &BreLds[buf][p * 2048 + wbase]);
      async16(&BimT[boff], &BimLds[buf][p * 2048 + wbase]);
    }
  };

  auto computeTile = [&](int buf) {
    bf16x8 aF[4], brF[4], biF[4];
    #pragma unroll
    for (int i = 0; i < 4; ++i)
      aF[i] = ldsFrag(Alds[buf], wr + i * 16 + m16, q);
    #pragma unroll
    for (int j = 0; j < 4; ++j) {
      brF[j] = ldsFrag(BreLds[buf], wc + j * 16 + m16, q);
      biF[j] = ldsFrag(BimLds[buf], wc + j * 16 + m16, q);
    }
    #pragma unroll
    for (int i = 0; i < 4; ++i)
      #pragma unroll
      for (int j = 0; j < 4; ++j) {
        accRe[i][j] = __builtin_amdgcn_mfma_f32_16x16x32_bf16(aF[i], brF[j], accRe[i][j], 0, 0, 0);
        accIm[i][j] = __builtin_amdgcn_mfma_f32_16x16x32_bf16(aF[i], biF[j], accIm[i][j], 0, 0, 0);
      }
  };

  stage(0, 0);
  __syncthreads();                  // vmcnt(0): buf0 ready
  int cur = 0;
  for (int kt = 32; kt < 1024; kt += 32) {
    stage(cur ^ 1, kt);             // issue next-tile loads (in flight during compute)
    computeTile(cur);
    __syncthreads();                // drains vmcnt(0): next tile ready
    cur ^= 1;
  }
  computeTile(cur);                 // last tile, no prefetch

  // fused elementwise recurrence epilogue
  #pragma unroll
  for (int j = 0; j < 4; ++j) {
    const int h  = hBase + wc + j * 16 + m16;
    const float g  = gamma[h];
    const float lr = lamRe[h];
    const float li = lamIm[h];
    #pragma unroll
    for (int i = 0; i < 4; ++i) {
      #pragma unroll
      for (int r = 0; r < 4; ++r) {
        const int row = mBase + wr + i * 16 + q * 4 + r;
        const size_t off = (size_t)row * DHID + h;
        const float ur = g * accRe[i][j][r];
        const float ui = g * accIm[i][j][r];
        const float sr = state_re[off];
        const float si = state_im[off];
        const float xr = sr * lr - si * li + ur;
        const float xi = sr * li + si * lr + ui;
        xre_out[off] = xr;
        xim_out[off] = xi;
        const size_t xoff = (size_t)row * (2 * DHID) + h;
        Xcat[xoff]        = to_bf16(xr);
        Xcat[xoff + DHID] = to_bf16(xi);
      }
    }
  }
}

// ---------------- GEMM2: y = Xcat @ Ccat + D*inputs ----------------
// Xcat [8192,4096] bf16; CcatT [1024,4096] bf16 ([n][k], rows n, k over 2H)

__global__ __launch_bounds__(256, 2) void gemm2_kernel(
    const bf16* __restrict__ Xcat,
    const bf16* __restrict__ CcatT,
    const float* __restrict__ Dvec,
    const float* __restrict__ inputs,
    float* __restrict__ y)
{
  __shared__ __align__(16) bf16 Alds[2][128 * 32];
  __shared__ __align__(16) bf16 Blds[2][128 * 32];

  const int tid   = threadIdx.x;
  const int mBase = blockIdx.y * 128;
  const int nBase = blockIdx.x * 128;
  const int lane  = tid & 63;
  const int wave  = tid >> 6;
  const int wr    = (wave >> 1) * 64;
  const int wc    = (wave & 1) * 64;
  const int m16   = lane & 15;
  const int q     = lane >> 4;

  floatx4 zero = {0.f, 0.f, 0.f, 0.f};
  floatx4 acc[4][4];
  #pragma unroll
  for (int i = 0; i < 4; ++i)
    #pragma unroll
    for (int j = 0; j < 4; ++j) acc[i][j] = zero;

  const int row0 = tid >> 2;
  const int wbase = wave * 512;

  auto stage = [&](int buf, int kt) {
    #pragma unroll
    for (int p = 0; p < 2; ++p) {
      const int r  = row0 + p * 64;
      const int ss = ((tid & 3) ^ ((r >> 1) & 3)) * 8;
      const size_t aoff = (size_t)(mBase + r) * 4096 + kt + ss;
      const size_t boff = (size_t)(nBase + r) * 4096 + kt + ss;
      async16(&Xcat[aoff],  &Alds[buf][p * 2048 + wbase]);
      async16(&CcatT[boff], &Blds[buf][p * 2048 + wbase]);
    }
  };

  auto computeTile = [&](int buf) {
    bf16x8 aF[4], bF[4];
    #pragma unroll
    for (int i = 0; i < 4; ++i)
      aF[i] = ldsFrag(Alds[buf], wr + i * 16 + m16, q);
    #pragma unroll
    for (int j = 0; j < 4; ++j)
      bF[j] = ldsFrag(Blds[buf], wc + j * 16 + m16, q);
    #pragma unroll
    for (int i = 0; i < 4; ++i)
      #pragma unroll
      for (int j = 0; j < 4; ++j)
        acc[i][j] = __builtin_amdgcn_mfma_f32_16x16x32_bf16(aF[i], bF[j], acc[i][j], 0, 0, 0);
  };

  stage(0, 0);
  __syncthreads();
  int cur = 0;
  for (int kt = 32; kt < 4096; kt += 32) {
    stage(cur ^ 1, kt);
    computeTile(cur);
    __syncthreads();
    cur ^= 1;
  }
  computeTile(cur);

  #pragma unroll
  for (int j = 0; j < 4; ++j) {
    const int n = nBase + wc + j * 16 + m16;
    const float dv = Dvec[n];
    #pragma unroll
    for (int i = 0; i < 4; ++i) {
      #pragma unroll
      for (int r = 0; r < 4; ++r) {
        const int row = mBase + wr + i * 16 + q * 4 + r;
        const size_t idx = (size_t)row * NREC + n;
        y[idx] = acc[i][j][r] + dv * inputs[idx];
      }
    }
  }
}

// ---------------- launch ----------------

extern "C" void kernel_launch(void* const* d_in, const int* in_sizes, int n_in,
                              void* d_out, int out_size, void* d_ws, size_t ws_size,
                              hipStream_t stream) {
  (void)in_sizes; (void)n_in; (void)out_size; (void)ws_size;

  const float* inputs   = (const float*)d_in[0];
  const float* state_re = (const float*)d_in[1];
  const float* state_im = (const float*)d_in[2];
  const float* B_re     = (const float*)d_in[3];
  const float* B_im     = (const float*)d_in[4];
  const float* C_re     = (const float*)d_in[5];
  const float* C_im     = (const float*)d_in[6];
  const float* Dvec     = (const float*)d_in[7];
  const float* nu       = (const float*)d_in[8];
  const float* theta    = (const float*)d_in[9];
  const float* gamma    = (const float*)d_in[10];

  float* out     = (float*)d_out;
  float* y_out   = out;
  float* xre_out = out + (size_t)BATCH * NREC;
  float* xim_out = xre_out + (size_t)BATCH * DHID;

  char* ws = (char*)d_ws;
  bf16*  A1    = (bf16*)(ws + 0);           // 16 MB: inputs bf16 [8192,1024]
  bf16*  BreT  = (bf16*)(ws + 16777216);    // 4 MB:  [2048,1024]
  bf16*  BimT  = (bf16*)(ws + 20971520);    // 4 MB
  bf16*  CcatT = (bf16*)(ws + 25165824);    // 8 MB:  [1024,4096] = [C_re; -C_im]^T
  bf16*  Xcat  = (bf16*)(ws + 33554432);    // 64 MB: [8192,4096]
  float* lamRe = (float*)(ws + 100663296);  // 8 KB
  float* lamIm = (float*)(ws + 100671488);  // 8 KB

  lam_kernel<<<dim3(DHID / 256), dim3(256), 0, stream>>>(nu, theta, lamRe, lamIm);
  convert_kernel<<<dim3((BATCH * NREC) / 1024), dim3(256), 0, stream>>>(inputs, A1);

  dim3 tb(32, 8);
  transpose_kernel<<<dim3(2048 / 32, 1024 / 32), tb, 0, stream>>>(B_re, 2048, BreT, 1024, 1.0f);
  transpose_kernel<<<dim3(2048 / 32, 1024 / 32), tb, 0, stream>>>(B_im, 2048, BimT, 1024, 1.0f);
  transpose_kernel<<<dim3(1024 / 32, 2048 / 32), tb, 0, stream>>>(C_re, 1024, CcatT, 4096, 1.0f);
  transpose_kernel<<<dim3(1024 / 32, 2048 / 32), tb, 0, stream>>>(C_im, 1024, CcatT + 2048, 4096, -1.0f);

  gemm1_kernel<<<dim3(DHID / 128, BATCH / 128), dim3(256), 0, stream>>>(
      A1, BreT, BimT, state_re, state_im, gamma, lamRe, lamIm, xre_out, xim_out, Xcat);

  gemm2_kernel<<<dim3(NREC / 128, BATCH / 128), dim3(256), 0, stream>>>(
      Xcat, CcatT, Dvec, inputs, y_out);
}

// Round 2
// 565.625 us; speedup vs baseline: 1.1325x; 1.1290x over previous
//
#include <hip/hip_runtime.h>
#include <hip/hip_bf16.h>

typedef __bf16 bf16;
typedef __attribute__((ext_vector_type(8))) __bf16 bf16x8;
typedef __attribute__((ext_vector_type(4))) float floatx4;

#define BATCH 8192
#define NREC  1024
#define DHID  2048

#define GLOBAL_AS __attribute__((address_space(1)))
#define LDS_AS    __attribute__((address_space(3)))

__device__ __forceinline__ bf16 to_bf16(float f) { return (bf16)f; }

// async global->LDS, 16 bytes per lane; LDS dest = wave-uniform base + lane*16
__device__ __forceinline__ void async16(const void* g, void* l) {
  __builtin_amdgcn_global_load_lds((const GLOBAL_AS unsigned int*)g,
                                   (LDS_AS unsigned int*)l, 16, 0, 0);
}

// Swizzled LDS fragment read: LDS tile is [128][32] bf16 (64 B rows, 4x 16B slots).
// Stored with slot s holding global slot s ^ ((row>>1)&3); read applies same XOR.
// Rows 0..7 then hit all 8 bank-quads -> 2-way aliasing (free) instead of 8-way.
// (verified round 1: SQ_LDS_BANK_CONFLICT -> 0)
__device__ __forceinline__ bf16x8 ldsFrag(const bf16* buf, int row, int q) {
  const int s = (q ^ ((row >> 1) & 3)) * 8;
  return *reinterpret_cast<const bf16x8*>(&buf[row * 32 + s]);
}

// ---------------- prep kernels ----------------

__global__ void lam_kernel(const float* __restrict__ nu, const float* __restrict__ theta,
                           float* __restrict__ lamRe, float* __restrict__ lamIm) {
  int h = blockIdx.x * blockDim.x + threadIdx.x;
  if (h < DHID) {
    float t = expf(-expf(nu[h]));
    lamRe[h] = t * cosf(theta[h]);
    lamIm[h] = t * sinf(theta[h]);
  }
}

// f32 -> bf16, 4 elements/thread
__global__ void convert_kernel(const float* __restrict__ src, bf16* __restrict__ dst) {
  int idx = blockIdx.x * blockDim.x + threadIdx.x;
  float4 v = reinterpret_cast<const float4*>(src)[idx];
  ushort4 pk;
  pk.x = __builtin_bit_cast(unsigned short, to_bf16(v.x));
  pk.y = __builtin_bit_cast(unsigned short, to_bf16(v.y));
  pk.z = __builtin_bit_cast(unsigned short, to_bf16(v.z));
  pk.w = __builtin_bit_cast(unsigned short, to_bf16(v.w));
  *reinterpret_cast<ushort4*>(dst + (size_t)idx * 4) = pk;
}

// dst[c*dstStride + r] = scale * src[r*C + c]; block (32,8); grid (C/32, R/32)
__global__ void transpose_kernel(const float* __restrict__ src, int C,
                                 bf16* __restrict__ dst, int dstStride, float scale) {
  __shared__ float tile[32][33];
  int c0 = blockIdx.x * 32, r0 = blockIdx.y * 32;
  #pragma unroll
  for (int i = 0; i < 32; i += 8) {
    tile[threadIdx.y + i][threadIdx.x] =
        src[(size_t)(r0 + threadIdx.y + i) * C + c0 + threadIdx.x];
  }
  __syncthreads();
  #pragma unroll
  for (int i = 0; i < 32; i += 8) {
    int c = c0 + threadIdx.y + i;
    dst[(size_t)c * dstStride + r0 + threadIdx.x] =
        to_bf16(scale * tile[threadIdx.x][threadIdx.y + i]);
  }
}

// ---------------- GEMM1: U_re/U_im = inputs @ B_{re,im}, fused recurrence epilogue ----
// A    [8192,1024] bf16 row-major
// BreT/BimT [2048,1024] bf16 (B^T layout: [h][k])
// out: xre/xim f32 [8192,2048]; Xcat bf16 [8192,4096] (cols 0..2047 = xre, 2048.. = xim)
//
// 512 threads, 8 waves (2M x 4N), per-wave output 64x32 (Re+Im).
// Accumulators: 16 floatx4 = 64 regs/thread (was 128) -> occupancy was the bottleneck.
// Double-buffered LDS, prefetch-before-compute, read-side XOR swizzle.

__global__ __launch_bounds__(512, 3) void gemm1_kernel(
    const bf16* __restrict__ A,
    const bf16* __restrict__ BreT,
    const bf16* __restrict__ BimT,
    const float* __restrict__ state_re,
    const float* __restrict__ state_im,
    const float* __restrict__ gamma,
    const float* __restrict__ lamRe,
    const float* __restrict__ lamIm,
    float* __restrict__ xre_out,
    float* __restrict__ xim_out,
    bf16* __restrict__ Xcat)
{
  __shared__ __align__(16) bf16 Alds[2][128 * 32];
  __shared__ __align__(16) bf16 BreLds[2][128 * 32];
  __shared__ __align__(16) bf16 BimLds[2][128 * 32];

  const int tid   = threadIdx.x;
  const int mBase = blockIdx.y * 128;
  const int hBase = blockIdx.x * 128;
  const int lane  = tid & 63;
  const int wave  = tid >> 6;        // 0..7
  const int wr    = (wave >> 2) * 64; // 0 or 64
  const int wc    = (wave & 3) * 32;  // 0,32,64,96
  const int m16   = lane & 15;
  const int q     = lane >> 4;

  floatx4 zero = {0.f, 0.f, 0.f, 0.f};
  floatx4 accRe[4][2], accIm[4][2];
  #pragma unroll
  for (int i = 0; i < 4; ++i)
    #pragma unroll
    for (int j = 0; j < 2; ++j) { accRe[i][j] = zero; accIm[i][j] = zero; }

  const int row0 = tid >> 2;          // 0..127: one 16B slot per thread covers the tile
  const int ss   = ((tid & 3) ^ ((row0 >> 1) & 3)) * 8;  // pre-swizzled source slot
  const int wbase = wave * 512;       // wave-uniform LDS base (elements)

  auto stage = [&](int buf, int kt) {
    const size_t aoff = (size_t)(mBase + row0) * 1024 + kt + ss;
    const size_t boff = (size_t)(hBase + row0) * 1024 + kt + ss;
    async16(&A[aoff],    &Alds[buf][wbase]);
    async16(&BreT[boff], &BreLds[buf][wbase]);
    async16(&BimT[boff], &BimLds[buf][wbase]);
  };

  auto computeTile = [&](int buf) {
    bf16x8 aF[4], brF[2], biF[2];
    #pragma unroll
    for (int i = 0; i < 4; ++i)
      aF[i] = ldsFrag(Alds[buf], wr + i * 16 + m16, q);
    #pragma unroll
    for (int j = 0; j < 2; ++j) {
      brF[j] = ldsFrag(BreLds[buf], wc + j * 16 + m16, q);
      biF[j] = ldsFrag(BimLds[buf], wc + j * 16 + m16, q);
    }
    #pragma unroll
    for (int i = 0; i < 4; ++i)
      #pragma unroll
      for (int j = 0; j < 2; ++j) {
        accRe[i][j] = __builtin_amdgcn_mfma_f32_16x16x32_bf16(aF[i], brF[j], accRe[i][j], 0, 0, 0);
        accIm[i][j] = __builtin_amdgcn_mfma_f32_16x16x32_bf16(aF[i], biF[j], accIm[i][j], 0, 0, 0);
      }
  };

  stage(0, 0);
  __syncthreads();                  // buf0 ready
  int cur = 0;
  for (int kt = 32; kt < 1024; kt += 32) {
    stage(cur ^ 1, kt);             // next-tile loads in flight during compute
    computeTile(cur);
    __syncthreads();                // drains vmcnt(0): next tile ready
    cur ^= 1;
  }
  computeTile(cur);                 // last tile, no prefetch

  // fused elementwise recurrence epilogue
  #pragma unroll
  for (int j = 0; j < 2; ++j) {
    const int h  = hBase + wc + j * 16 + m16;
    const float g  = gamma[h];
    const float lr = lamRe[h];
    const float li = lamIm[h];
    #pragma unroll
    for (int i = 0; i < 4; ++i) {
      #pragma unroll
      for (int r = 0; r < 4; ++r) {
        const int row = mBase + wr + i * 16 + q * 4 + r;
        const size_t off = (size_t)row * DHID + h;
        const float ur = g * accRe[i][j][r];
        const float ui = g * accIm[i][j][r];
        const float sr = state_re[off];
        const float si = state_im[off];
        const float xr = sr * lr - si * li + ur;
        const float xi = sr * li + si * lr + ui;
        xre_out[off] = xr;
        xim_out[off] = xi;
        const size_t xoff = (size_t)row * (2 * DHID) + h;
        Xcat[xoff]        = to_bf16(xr);
        Xcat[xoff + DHID] = to_bf16(xi);
      }
    }
  }
}

// ---------------- GEMM2: y = Xcat @ Ccat + D*inputs ----------------
// Xcat [8192,4096] bf16; CcatT [1024,4096] bf16 ([n][k], rows n, k over 2H)
// 512 threads, 8 waves (2M x 4N), per-wave output 64x32.

__global__ __launch_bounds__(512, 4) void gemm2_kernel(
    const bf16* __restrict__ Xcat,
    const bf16* __restrict__ CcatT,
    const float* __restrict__ Dvec,
    const float* __restrict__ inputs,
    float* __restrict__ y)
{
  __shared__ __align__(16) bf16 Alds[2][128 * 32];
  __shared__ __align__(16) bf16 Blds[2][128 * 32];

  const int tid   = threadIdx.x;
  const int mBase = blockIdx.y * 128;
  const int nBase = blockIdx.x * 128;
  const int lane  = tid & 63;
  const int wave  = tid >> 6;
  const int wr    = (wave >> 2) * 64;
  const int wc    = (wave & 3) * 32;
  const int m16   = lane & 15;
  const int q     = lane >> 4;

  floatx4 zero = {0.f, 0.f, 0.f, 0.f};
  floatx4 acc[4][2];
  #pragma unroll
  for (int i = 0; i < 4; ++i)
    #pragma unroll
    for (int j = 0; j < 2; ++j) acc[i][j] = zero;

  const int row0 = tid >> 2;
  const int ss   = ((tid & 3) ^ ((row0 >> 1) & 3)) * 8;
  const int wbase = wave * 512;

  auto stage = [&](int buf, int kt) {
    const size_t aoff = (size_t)(mBase + row0) * 4096 + kt + ss;
    const size_t boff = (size_t)(nBase + row0) * 4096 + kt + ss;
    async16(&Xcat[aoff],  &Alds[buf][wbase]);
    async16(&CcatT[boff], &Blds[buf][wbase]);
  };

  auto computeTile = [&](int buf) {
    bf16x8 aF[4], bF[2];
    #pragma unroll
    for (int i = 0; i < 4; ++i)
      aF[i] = ldsFrag(Alds[buf], wr + i * 16 + m16, q);
    #pragma unroll
    for (int j = 0; j < 2; ++j)
      bF[j] = ldsFrag(Blds[buf], wc + j * 16 + m16, q);
    #pragma unroll
    for (int i = 0; i < 4; ++i)
      #pragma unroll
      for (int j = 0; j < 2; ++j)
        acc[i][j] = __builtin_amdgcn_mfma_f32_16x16x32_bf16(aF[i], bF[j], acc[i][j], 0, 0, 0);
  };

  stage(0, 0);
  __syncthreads();
  int cur = 0;
  for (int kt = 32; kt < 4096; kt += 32) {
    stage(cur ^ 1, kt);
    computeTile(cur);
    __syncthreads();
    cur ^= 1;
  }
  computeTile(cur);

  #pragma unroll
  for (int j = 0; j < 2; ++j) {
    const int n = nBase + wc + j * 16 + m16;
    const float dv = Dvec[n];
    #pragma unroll
    for (int i = 0; i < 4; ++i) {
      #pragma unroll
      for (int r = 0; r < 4; ++r) {
        const int row = mBase + wr + i * 16 + q * 4 + r;
        const size_t idx = (size_t)row * NREC + n;
        y[idx] = acc[i][j][r] + dv * inputs[idx];
      }
    }
  }
}

// ---------------- launch ----------------

extern "C" void kernel_launch(void* const* d_in, const int* in_sizes, int n_in,
                              void* d_out, int out_size, void* d_ws, size_t ws_size,
                              hipStream_t stream) {
  (void)in_sizes; (void)n_in; (void)out_size; (void)ws_size;

  const float* inputs   = (const float*)d_in[0];
  const float* state_re = (const float*)d_in[1];
  const float* state_im = (const float*)d_in[2];
  const float* B_re     = (const float*)d_in[3];
  const float* B_im     = (const float*)d_in[4];
  const float* C_re     = (const float*)d_in[5];
  const float* C_im     = (const float*)d_in[6];
  const float* Dvec     = (const float*)d_in[7];
  const float* nu       = (const float*)d_in[8];
  const float* theta    = (const float*)d_in[9];
  const float* gamma    = (const float*)d_in[10];

  float* out     = (float*)d_out;
  float* y_out   = out;
  float* xre_out = out + (size_t)BATCH * NREC;
  float* xim_out = xre_out + (size_t)BATCH * DHID;

  char* ws = (char*)d_ws;
  bf16*  A1    = (bf16*)(ws + 0);           // 16 MB: inputs bf16 [8192,1024]
  bf16*  BreT  = (bf16*)(ws + 16777216);    // 4 MB:  [2048,1024]
  bf16*  BimT  = (bf16*)(ws + 20971520);    // 4 MB
  bf16*  CcatT = (bf16*)(ws + 25165824);    // 8 MB:  [1024,4096] = [C_re; -C_im]^T
  bf16*  Xcat  = (bf16*)(ws + 33554432);    // 64 MB: [8192,4096]
  float* lamRe = (float*)(ws + 100663296);  // 8 KB
  float* lamIm = (float*)(ws + 100671488);  // 8 KB

  lam_kernel<<<dim3(DHID / 256), dim3(256), 0, stream>>>(nu, theta, lamRe, lamIm);
  convert_kernel<<<dim3((BATCH * NREC) / 1024), dim3(256), 0, stream>>>(inputs, A1);

  dim3 tb(32, 8);
  transpose_kernel<<<dim3(2048 / 32, 1024 / 32), tb, 0, stream>>>(B_re, 2048, BreT, 1024, 1.0f);
  transpose_kernel<<<dim3(2048 / 32, 1024 / 32), tb, 0, stream>>>(B_im, 2048, BimT, 1024, 1.0f);
  transpose_kernel<<<dim3(1024 / 32, 2048 / 32), tb, 0, stream>>>(C_re, 1024, CcatT, 4096, 1.0f);
  transpose_kernel<<<dim3(1024 / 32, 2048 / 32), tb, 0, stream>>>(C_im, 1024, CcatT + 2048, 4096, -1.0f);

  gemm1_kernel<<<dim3(DHID / 128, BATCH / 128), dim3(512), 0, stream>>>(
      A1, BreT, BimT, state_re, state_im, gamma, lamRe, lamIm, xre_out, xim_out, Xcat);

  gemm2_kernel<<<dim3(NREC / 128, BATCH / 128), dim3(512), 0, stream>>>(
      Xcat, CcatT, Dvec, inputs, y_out);
}